// Round 1
// baseline (593.574 us; speedup 1.0000x reference)
//
#include <hip/hip_runtime.h>
#include <stdint.h>

#define MM 8192
#define NN 4096
#define KK 4096

typedef __attribute__((ext_vector_type(8))) short short8;
typedef __attribute__((ext_vector_type(4))) float floatx4;

// fp32 -> bf16 round-to-nearest-even (inputs are finite normals; no NaN path needed)
__device__ inline unsigned short f2bf(float f) {
    unsigned int u = __float_as_uint(f);
    u += 0x7FFFu + ((u >> 16) & 1u);
    return (unsigned short)(u >> 16);
}

// Convert x [8192,4096] fp32 -> bf16, 4 elems/thread, fully coalesced.
__global__ void prep_x_kernel(const float* __restrict__ x, unsigned short* __restrict__ xb) {
    int i = blockIdx.x * 256 + threadIdx.x;   // quad index, total MM*KK/4
    const float4* x4 = (const float4*)x;
    float4 v = x4[i];
    ushort4 o;
    o.x = f2bf(v.x); o.y = f2bf(v.y); o.z = f2bf(v.z); o.w = f2bf(v.w);
    *(ushort4*)(xb + (size_t)i * 4) = o;
}

// Build W [4096,4096] bf16 row-major: W[r][c] = vals[4095 - r + c].
__global__ void prep_w_kernel(const float* __restrict__ vals, unsigned short* __restrict__ w) {
    int t = blockIdx.x * 256 + threadIdx.x;   // quad index, total NN*KK/4
    int row = t >> 10;            // KK/4 = 1024 quads per row
    int col = (t & 1023) << 2;
    int vi = (NN - 1) - row + col;            // in [0, 8190]
    ushort4 o;
    o.x = f2bf(vals[vi]);
    o.y = f2bf(vals[vi + 1]);
    o.z = f2bf(vals[vi + 2]);
    o.w = f2bf(vals[vi + 3]);
    *(ushort4*)(w + ((size_t)row << 12) + col) = o;
}

#define GLOAD_LDS16(g, l)                                              \
    __builtin_amdgcn_global_load_lds(                                  \
        (__attribute__((address_space(1))) void*)(g),                  \
        (__attribute__((address_space(3))) void*)(l), 16, 0, 0)

// C[m,n] = sum_k A[m,k] * B[n,k]   (B^T GEMM; A=x bf16, B=W bf16 row-major [N,K])
// m97 structure: 128x128 tile, 4 waves in 2x2, each wave 4x4 of 16x16x32 MFMA,
// global_load_lds width=16 staging, single LDS buffer, 2 barriers per K-step.
__global__ __launch_bounds__(256) void gemm_kernel(
        const unsigned short* __restrict__ A,
        const unsigned short* __restrict__ B,
        float* __restrict__ C) {
    __shared__ unsigned short ldsA[128 * 32];
    __shared__ unsigned short ldsB[128 * 32];

    const int tid  = threadIdx.x;
    const int lane = tid & 63;
    const int w    = tid >> 6;
    const int n0 = blockIdx.x * 128;
    const int m0 = blockIdx.y * 128;

    const int lrow  = lane >> 2;        // 0..15: row within a 16-row staging group
    const int lcol  = (lane & 3) * 8;   // 0,8,16,24: element col within 32-wide tile
    const int quad  = lane >> 4;        // 0..3
    const int l16   = lane & 15;
    const int wm    = (w >> 1) * 64;    // wave's 64x64 sub-tile
    const int wn    = (w & 1) * 64;

    // staging: wave w handles tile rows [w*32, w*32+32) of both A and B tiles
    const unsigned short* aSrc0 = A + (m0 + w * 32 + lrow) * KK + lcol;
    const unsigned short* aSrc1 = aSrc0 + 16 * KK;
    const unsigned short* bSrc0 = B + (n0 + w * 32 + lrow) * KK + lcol;
    const unsigned short* bSrc1 = bSrc0 + 16 * KK;
    unsigned short* aDst0 = &ldsA[(w * 32) * 32];   // wave-uniform; HW adds lane*16B
    unsigned short* aDst1 = aDst0 + 16 * 32;
    unsigned short* bDst0 = &ldsB[(w * 32) * 32];
    unsigned short* bDst1 = bDst0 + 16 * 32;

    floatx4 acc[4][4] = {};

    for (int k0 = 0; k0 < KK; k0 += 32) {
        __syncthreads();
        GLOAD_LDS16(aSrc0 + k0, aDst0);
        GLOAD_LDS16(aSrc1 + k0, aDst1);
        GLOAD_LDS16(bSrc0 + k0, bDst0);
        GLOAD_LDS16(bSrc1 + k0, bDst1);
        __syncthreads();

        short8 af[4], bfr[4];
#pragma unroll
        for (int i = 0; i < 4; ++i)
            af[i] = *(const short8*)&ldsA[(wm + i * 16 + l16) * 32 + quad * 8];
#pragma unroll
        for (int j = 0; j < 4; ++j)
            bfr[j] = *(const short8*)&ldsB[(wn + j * 16 + l16) * 32 + quad * 8];
#pragma unroll
        for (int i = 0; i < 4; ++i)
#pragma unroll
            for (int j = 0; j < 4; ++j)
                acc[i][j] = __builtin_amdgcn_mfma_f32_16x16x32_bf16(
                    af[i], bfr[j], acc[i][j], 0, 0, 0);
    }

    // Epilogue: C/D layout col = lane&15, row = quad*4 + reg (m89-verified)
    float* cW = C + (m0 + wm) * NN + (n0 + wn);
#pragma unroll
    for (int i = 0; i < 4; ++i) {
#pragma unroll
        for (int j = 0; j < 4; ++j) {
            float* cp = cW + (i * 16 + quad * 4) * NN + j * 16 + l16;
#pragma unroll
            for (int r = 0; r < 4; ++r)
                cp[r * NN] = acc[i][j][r];
        }
    }
}

extern "C" void kernel_launch(void* const* d_in, const int* in_sizes, int n_in,
                              void* d_out, int out_size, void* d_ws, size_t ws_size,
                              hipStream_t stream) {
    const float* x    = (const float*)d_in[0];
    const float* vals = (const float*)d_in[1];
    float* out = (float*)d_out;

    unsigned short* xb = (unsigned short*)d_ws;                 // 67.1 MB
    unsigned short* wb = xb + (size_t)MM * KK;                  // +33.6 MB = 100.7 MB total

    prep_x_kernel<<<MM * KK / 4 / 256, 256, 0, stream>>>(x, xb);
    prep_w_kernel<<<NN * KK / 4 / 256, 256, 0, stream>>>(vals, wb);

    dim3 grid(NN / 128, MM / 128);
    gemm_kernel<<<grid, 256, 0, stream>>>(xb, wb, out);
}

// Round 2
// 572.274 us; speedup vs baseline: 1.0372x; 1.0372x over previous
//
#include <hip/hip_runtime.h>
#include <stdint.h>

#define MM 8192
#define NN 4096
#define KK 4096

typedef __attribute__((ext_vector_type(8))) short short8;
typedef __attribute__((ext_vector_type(4))) float floatx4;
typedef int int4a __attribute__((ext_vector_type(4), aligned(4)));  // 4B-aligned 16B load

// fp32 -> bf16 round-to-nearest-even
__device__ inline unsigned short f2bf(float f) {
    unsigned int u = __float_as_uint(f);
    u += 0x7FFFu + ((u >> 16) & 1u);
    return (unsigned short)(u >> 16);
}

// Convert x [8192,4096] fp32 -> bf16, 4 elems/thread, coalesced.
__global__ void prep_x_kernel(const float* __restrict__ x, unsigned short* __restrict__ xb) {
    int i = blockIdx.x * 256 + threadIdx.x;
    const float4* x4 = (const float4*)x;
    float4 v = x4[i];
    ushort4 o;
    o.x = f2bf(v.x); o.y = f2bf(v.y); o.z = f2bf(v.z); o.w = f2bf(v.w);
    *(ushort4*)(xb + (size_t)i * 4) = o;
}

// vals (8191 fp32) -> two bf16 copies: vlo[i]=vals[i], vhi[i]=vals[i+1].
// Dual copy makes any even byte offset 4-byte aligned in one of the two.
__global__ void prep_vals_kernel(const float* __restrict__ vals,
                                 unsigned short* __restrict__ vlo,
                                 unsigned short* __restrict__ vhi) {
    int i = blockIdx.x * 256 + threadIdx.x;
    if (i < KK + NN - 1) {
        unsigned short s = f2bf(vals[i]);
        vlo[i] = s;
        if (i > 0) vhi[i - 1] = s;
    }
}

#define GLOAD_LDS16(g, l)                                              \
    __builtin_amdgcn_global_load_lds(                                  \
        (__attribute__((address_space(1))) void*)(g),                  \
        (__attribute__((address_space(3))) void*)(l), 16, 0, 0)

// C[m,n] = sum_k A[m,k] * W[n,k],  W[n,k] = vals[4095 - n + k] (Toeplitz).
// A staged in LDS (128x64 tile, XOR-8 swizzled, global_load_lds w=16).
// B fragments read directly from the 16KB L1-resident bf16 vals copies:
// B-frag(j,kh) = vals[4095 - n + k0 + kh*32 + quad*8 .. +7], contiguous.
__global__ __launch_bounds__(256) void gemm_kernel(
        const unsigned short* __restrict__ A,
        const unsigned short* __restrict__ vlo,
        const unsigned short* __restrict__ vhi,
        float* __restrict__ C) {
    __shared__ unsigned short ldsA[128 * 64];   // 16 KB, rows of 64 elems (128B)

    const int tid  = threadIdx.x;
    const int lane = tid & 63;
    const int w    = tid >> 6;
    const int n0 = blockIdx.x * 128;
    const int m0 = blockIdx.y * 128;

    const int quad = lane >> 4;         // 0..3 (MFMA k-group)
    const int l16  = lane & 15;
    const int wm   = (w >> 1) * 64;     // wave's 64x64 sub-tile of the 128x128 block
    const int wn   = (w & 1) * 64;

    // ---- A staging: wave w stages rows [w*32, w*32+32), 4 GLL of 8 rows each.
    // Lane l -> row (l>>3), slot (l&7); slot s of row r holds chunk s^(r&7).
    const int lr8  = lane >> 3;         // 0..7: row within 8-row group
    const int cg   = (lane & 7) ^ (lr8 & 7);   // swizzled global k-chunk
    const unsigned short* aSrc = A + (size_t)(m0 + w * 32 + lr8) * KK + cg * 8;
    unsigned short* aDst = &ldsA[(w * 32) * 64];   // wave-uniform; HW adds lane*16B

    // ---- B pointers: idx(j) = 4095 - (n0+wn+l16) - j*16 + quad*8 (+k0, +kh*32).
    // Parity of idx is k-invariant -> pointer select hoists out of the loop.
    const unsigned short* bptr[4];
#pragma unroll
    for (int j = 0; j < 4; ++j) {
        int idx0 = (NN - 1) - (n0 + wn + l16) - j * 16 + quad * 8;
        bptr[j] = (idx0 & 1) ? (vhi + (idx0 - 1)) : (vlo + idx0);
    }

    floatx4 acc[4][4] = {};

    for (int k0 = 0; k0 < KK; k0 += 64) {
        __syncthreads();
#pragma unroll
        for (int g = 0; g < 4; ++g)
            GLOAD_LDS16(aSrc + (size_t)g * 8 * KK + k0, aDst + g * 8 * 64);
        __syncthreads();

#pragma unroll
        for (int kh = 0; kh < 2; ++kh) {
            short8 af[4], bfr[4];
#pragma unroll
            for (int i = 0; i < 4; ++i)
                af[i] = *(const short8*)&ldsA[(wm + i * 16 + l16) * 64 +
                                              (((kh * 4 + quad) ^ (l16 & 7)) * 8)];
#pragma unroll
            for (int j = 0; j < 4; ++j) {
                int4a t = *(const int4a*)(bptr[j] + kh * 32);
                __builtin_memcpy(&bfr[j], &t, 16);
            }
#pragma unroll
            for (int i = 0; i < 4; ++i)
#pragma unroll
                for (int j = 0; j < 4; ++j)
                    acc[i][j] = __builtin_amdgcn_mfma_f32_16x16x32_bf16(
                        af[i], bfr[j], acc[i][j], 0, 0, 0);
        }
#pragma unroll
        for (int j = 0; j < 4; ++j) bptr[j] += 64;
    }

    // Epilogue: C/D layout col = lane&15, row = quad*4 + reg (m89-verified)
    float* cW = C + (size_t)(m0 + wm) * NN + (n0 + wn);
#pragma unroll
    for (int i = 0; i < 4; ++i) {
#pragma unroll
        for (int j = 0; j < 4; ++j) {
            float* cp = cW + (size_t)(i * 16 + quad * 4) * NN + j * 16 + l16;
#pragma unroll
            for (int r = 0; r < 4; ++r)
                cp[(size_t)r * NN] = acc[i][j][r];
        }
    }
}

extern "C" void kernel_launch(void* const* d_in, const int* in_sizes, int n_in,
                              void* d_out, int out_size, void* d_ws, size_t ws_size,
                              hipStream_t stream) {
    const float* x    = (const float*)d_in[0];
    const float* vals = (const float*)d_in[1];
    float* out = (float*)d_out;

    unsigned short* xb  = (unsigned short*)d_ws;          // 67.1 MB
    unsigned short* vlo = xb + (size_t)MM * KK;           // 16.4 KB
    unsigned short* vhi = vlo + 8192;                     // 16.4 KB

    prep_x_kernel<<<MM * KK / 4 / 256, 256, 0, stream>>>(x, xb);
    prep_vals_kernel<<<(KK + NN - 1 + 255) / 256, 256, 0, stream>>>(vals, vlo, vhi);

    dim3 grid(NN / 128, MM / 128);
    gemm_kernel<<<grid, 256, 0, stream>>>(xb, vlo, vhi, out);
}